// Round 22
// baseline (160.804 us; speedup 1.0000x reference)
//
#include <hip/hip_runtime.h>

#define TB 4
#define TF 4096
#define DIN 1024
#define DK 128
#define M_TOT (TB * TF)  // 16384

typedef __attribute__((ext_vector_type(8))) short sh8;
typedef __attribute__((ext_vector_type(4))) float f32x4;

#if __has_builtin(__builtin_amdgcn_exp2f)
#define EXP2(x) __builtin_amdgcn_exp2f(x)
#else
#define EXP2(x) exp2f(x)
#endif

__device__ __forceinline__ unsigned short f2bf(float f) {
  unsigned int u = __builtin_bit_cast(unsigned int, f);
  u += 0x7FFFu + ((u >> 16) & 1u);
  return (unsigned short)(u >> 16);
}

__device__ __forceinline__ float bf2f(unsigned short u) {
  unsigned int x = ((unsigned int)u) << 16;
  return __builtin_bit_cast(float, x);
}

// Wf in MFMA-fragment order: Wf[((p*8 + t)*32 + ks)*512 + lane*8 + j]
//   = bf16(W_p[k = ks*32 + (lane>>4)*8 + j][col = t*16 + (lane&15)])
__global__ __launch_bounds__(256) void prep_wt_kernel(
    const float* __restrict__ Wq, const float* __restrict__ Wk,
    const float* __restrict__ Wv, unsigned short* __restrict__ Wf) {
  int idx = blockIdx.x * 256 + threadIdx.x;  // [0, 3*8*32*512)
  int j = idx & 7;
  int lane = (idx >> 3) & 63;
  int ks = (idx >> 9) & 31;
  int t = (idx >> 14) & 7;
  int p = idx >> 17;
  int col = t * 16 + (lane & 15);
  int k = ks * 32 + (lane >> 4) * 8 + j;
  const float* W = (p == 0) ? Wq : (p == 1) ? Wk : Wv;
  Wf[idx] = f2bf(W[k * DK + col]);
}

// Fused QKV projection. 512 threads = 8 waves; block = 64 rows of x.
// BK=64, double-buffered x tile, one barrier per tile (R17-proven).
// Wave w owns 16 cols for all 3 projections. Q pre-scaled by
// log2(e)/sqrt(128). V stored transposed.
__global__ __launch_bounds__(512, 2) void proj_kernel(
    const float* __restrict__ x,            // [M_TOT][DIN]
    const unsigned short* __restrict__ Wf,  // fragment-ordered weights
    const float* __restrict__ bq, const float* __restrict__ bk,
    const float* __restrict__ bv,
    unsigned short* __restrict__ Qb,  // [M_TOT][DK] bf16 (pre-scaled)
    unsigned short* __restrict__ Kb,  // [M_TOT][DK] bf16
    unsigned short* __restrict__ VT)  // [TB][DK][TF] bf16
{
  const int tid = threadIdx.x;
  const int wave = tid >> 6;  // 0..7 = col tile
  const int lane = tid & 63;
  const int lr = lane & 15;
  const int lg = lane >> 4;
  const int m0 = blockIdx.x * 64;
  const int col = wave * 16 + lr;

  __shared__ unsigned short Xlds[2][64 * 68];  // [row][k], pad 64->68

  f32x4 acc[3][4];
  const f32x4 z4 = {0.f, 0.f, 0.f, 0.f};
#pragma unroll
  for (int p = 0; p < 3; ++p)
#pragma unroll
    for (int m = 0; m < 4; ++m) acc[p][m] = z4;

  const int xr = tid >> 3;        // 0..63
  const int xk8 = (tid & 7) * 8;  // 0..56
  const float* xrow = x + (size_t)(m0 + xr) * DIN + xk8;

  // prologue: stage tile 0 into buffer 0
  {
    const float4 f0 = *(const float4*)(xrow);
    const float4 f1 = *(const float4*)(xrow + 4);
    union { sh8 v; unsigned short u[8]; } U;
    U.u[0] = f2bf(f0.x); U.u[1] = f2bf(f0.y);
    U.u[2] = f2bf(f0.z); U.u[3] = f2bf(f0.w);
    U.u[4] = f2bf(f1.x); U.u[5] = f2bf(f1.y);
    U.u[6] = f2bf(f1.z); U.u[7] = f2bf(f1.w);
    *(sh8*)&Xlds[0][xr * 68 + xk8] = U.v;
  }
  __syncthreads();

  for (int t = 0; t < DIN / 64; ++t) {
    const int k0 = t * 64;
    const int cur = t & 1;

    // stage tile t+1 into buf^1 (buf^1 free since end of tile t-1)
    if (t + 1 < DIN / 64) {
      const float4 f0 = *(const float4*)(xrow + k0 + 64);
      const float4 f1 = *(const float4*)(xrow + k0 + 68);
      union { sh8 v; unsigned short u[8]; } U;
      U.u[0] = f2bf(f0.x); U.u[1] = f2bf(f0.y);
      U.u[2] = f2bf(f0.z); U.u[3] = f2bf(f0.w);
      U.u[4] = f2bf(f1.x); U.u[5] = f2bf(f1.y);
      U.u[6] = f2bf(f1.z); U.u[7] = f2bf(f1.w);
      *(sh8*)&Xlds[cur ^ 1][xr * 68 + xk8] = U.v;
    }

    sh8 a[4][2];
#pragma unroll
    for (int m = 0; m < 4; ++m)
#pragma unroll
      for (int s = 0; s < 2; ++s)
        a[m][s] =
            *(const sh8*)&Xlds[cur][(m * 16 + lr) * 68 + s * 32 + lg * 8];
#pragma unroll
    for (int p = 0; p < 3; ++p) {
#pragma unroll
      for (int s = 0; s < 2; ++s) {
        sh8 b = *(const sh8*)(Wf +
                              ((size_t)((p * 8 + wave) * 32 + (k0 >> 5) + s)) *
                                  512 +
                              lane * 8);
#pragma unroll
        for (int m = 0; m < 4; ++m)
          acc[p][m] = __builtin_amdgcn_mfma_f32_16x16x32_bf16(a[m][s], b,
                                                              acc[p][m], 0, 0,
                                                              0);
      }
    }
    __syncthreads();  // staging of t+1 visible; reads of cur complete
  }

  // log2(e)/sqrt(128): softmax computed base-2 downstream
  const float scale = 0.12751744f;
  const int b_idx = m0 >> 12;
  const float add_q = bq[col];
  const float add_k = bk[col];
  const float add_v = bv[col];
#pragma unroll
  for (int m = 0; m < 4; ++m) {
    const int rowbase = m0 + m * 16 + lg * 4;
#pragma unroll
    for (int r = 0; r < 4; ++r) {
      Qb[(size_t)(rowbase + r) * DK + col] =
          f2bf((acc[0][m][r] + add_q) * scale);
      Kb[(size_t)(rowbase + r) * DK + col] = f2bf(acc[1][m][r] + add_k);
    }
    const int fbase = (m0 & (TF - 1)) + m * 16 + lg * 4;
    ushort4 pv;
    pv.x = f2bf(acc[2][m][0] + add_v);
    pv.y = f2bf(acc[2][m][1] + add_v);
    pv.z = f2bf(acc[2][m][2] + add_v);
    pv.w = f2bf(acc[2][m][3] + add_v);
    *(ushort4*)(VT + ((size_t)b_idx * DK + col) * TF + fbase) = pv;
  }
}

// Flash attention, split-KV (SPLIT=4). K fragments read DIRECTLY FROM GLOBAL
// (K tile = 16 KB, L1-resident; all 8 waves share it -> L1 hits) — removes
// Klds + its staging entirely (~40% of LDS-pipe ops). V stays in LDS
// (8 KB-stride V^T reads would thrash L1 — R4 lesson). Per-wave P-LDS
// exchange. LDS = 18432 + 9216 = 27648 B. 8 waves/block, QBLK=16/wave,
// swapped-operand QK^T, base-2 softmax + defer-max + setprio. Partials bf16.
template <int SPLIT>
__global__ __launch_bounds__(512) void attn_part_kernel(
    const unsigned short* __restrict__ Qb, const unsigned short* __restrict__ Kb,
    const unsigned short* __restrict__ VT, unsigned short* __restrict__ Opart,
    float* __restrict__ Mpart, float* __restrict__ Lpart,
    float* __restrict__ out) {
  constexpr int CHUNK = TF / SPLIT;
  const int tid = threadIdx.x;
  const int lane = tid & 63;
  const int lr = lane & 15;
  const int lg = lane >> 4;

  // XCD swizzle: 2 XCDs per batch so K/V (2 MB bf16/batch) stays L2-resident.
  const int bid = blockIdx.x;  // grid = 128*SPLIT
  const int xcd = bid & 7;
  const int batch = xcd >> 1;
  const int idb = ((bid >> 3) << 1) | (xcd & 1);  // 0 .. 32*SPLIT-1
  const int slot = idb / SPLIT;                   // 0..31
  const int chunk = idb % SPLIT;
  const int wave = tid >> 6;  // 0..7
  const int q0 = batch * TF + slot * 128 + wave * 16;
  const int kbase = chunk * CHUNK;

  __shared__ unsigned short Vlds[128 * 72];   // 128 dv x 64 kv (pad->72)
  __shared__ unsigned short Plds[8][16 * 72]; // per-wave P[q][kv]
  unsigned short* Pw = &Plds[wave][0];

  const unsigned short* Qp = Qb + (size_t)q0 * DK;
  const unsigned short* Kp = Kb + (size_t)batch * TF * DK;
  const unsigned short* Vp = VT + (size_t)batch * DK * TF;

  sh8 aq[4];
#pragma unroll
  for (int dd = 0; dd < 4; ++dd)
    aq[dd] = *(const sh8*)(Qp + lr * DK + dd * 32 + lg * 8);

  const f32x4 z4 = {0.f, 0.f, 0.f, 0.f};
  f32x4 ot[8];  // ot[nb][r] = O^T[d = nb*16 + lg*4 + r][q = lr]
#pragma unroll
  for (int nb = 0; nb < 8; ++nb) ot[nb] = z4;
  float mrow = -1e30f, lrow = 0.f;  // m in log2 units

  for (int kk0 = kbase; kk0 < kbase + CHUNK; kk0 += 64) {
    __syncthreads();
#pragma unroll
    for (int i = 0; i < 2; ++i) {  // stage V^T tile 128x64 (512 threads)
      int c = tid + i * 512;
      int row = c >> 3, c8 = c & 7;
      *(uint4*)&Vlds[row * 72 + c8 * 8] =
          *(const uint4*)(Vp + (size_t)row * TF + kk0 + c8 * 8);
    }
    __syncthreads();

    // S^T = K Q^T: st[c][r] = S[q=lr][kv = c*16 + lg*4 + r] (log2 units)
    // K fragments straight from global: K tile (16 KB) is L1-resident and
    // shared by all 8 waves of the block.
    f32x4 st[4];
#pragma unroll
    for (int c = 0; c < 4; ++c) st[c] = z4;
    __builtin_amdgcn_s_setprio(1);
#pragma unroll
    for (int dd = 0; dd < 4; ++dd) {
#pragma unroll
      for (int c = 0; c < 4; ++c) {
        sh8 kb = *(const sh8*)(Kp + (size_t)(kk0 + c * 16 + lr) * DK + dd * 32 +
                               lg * 8);
        st[c] =
            __builtin_amdgcn_mfma_f32_16x16x32_bf16(kb, aq[dd], st[c], 0, 0, 0);
      }
    }
    __builtin_amdgcn_s_setprio(0);

    // online softmax (base-2): lane owns q-row lr; v_max3-friendly tree
    float mx;
    {
      float m0a = fmaxf(fmaxf(st[0][0], st[0][1]), st[0][2]);
      float m0b = fmaxf(fmaxf(st[0][3], st[1][0]), st[1][1]);
      float m0c = fmaxf(fmaxf(st[1][2], st[1][3]), st[2][0]);
      float m0d = fmaxf(fmaxf(st[2][1], st[2][2]), st[2][3]);
      float m0e = fmaxf(fmaxf(st[3][0], st[3][1]), st[3][2]);
      float m1a = fmaxf(fmaxf(m0a, m0b), m0c);
      float m1b = fmaxf(fmaxf(m0d, m0e), st[3][3]);
      mx = fmaxf(m1a, m1b);
    }
    mx = fmaxf(mx, __shfl_xor(mx, 16));
    mx = fmaxf(mx, __shfl_xor(mx, 32));

    // defer-max: skip rescale while tile max stays within THR of running max
    if (!__all(mx - mrow <= 11.5f)) {
      const float mnew = fmaxf(mrow, mx);
      const float al = EXP2(mrow - mnew);
      lrow *= al;
#pragma unroll
      for (int nb = 0; nb < 8; ++nb)
#pragma unroll
        for (int r = 0; r < 4; ++r) ot[nb][r] *= al;
      mrow = mnew;
    }

    // P = exp2(S - m); write P row into wave-private LDS (no barrier needed:
    // same wave writes then reads, lgkmcnt orders it)
    float rs = 0.f;
#pragma unroll
    for (int c = 0; c < 4; ++c) {
      float p0 = EXP2(st[c][0] - mrow);
      float p1 = EXP2(st[c][1] - mrow);
      float p2 = EXP2(st[c][2] - mrow);
      float p3 = EXP2(st[c][3] - mrow);
      rs += p0 + p1 + p2 + p3;
      ushort4 w;
      w.x = f2bf(p0); w.y = f2bf(p1); w.z = f2bf(p2); w.w = f2bf(p3);
      *(ushort4*)&Pw[lr * 72 + c * 16 + lg * 4] = w;
    }
    rs += __shfl_xor(rs, 16);
    rs += __shfl_xor(rs, 32);
    lrow += rs;

    // O^T += V^T P^T; B-fragment pa = P[q=lr][kv=ks*32+lg*8 .. +7] from LDS
#pragma unroll
    for (int ks = 0; ks < 2; ++ks) {
      sh8 pa = *(const sh8*)&Pw[lr * 72 + ks * 32 + lg * 8];
      __builtin_amdgcn_s_setprio(1);
#pragma unroll
      for (int nb = 0; nb < 8; ++nb) {
        sh8 vb = *(const sh8*)&Vlds[(nb * 16 + lr) * 72 + ks * 32 + lg * 8];
        ot[nb] =
            __builtin_amdgcn_mfma_f32_16x16x32_bf16(vb, pa, ot[nb], 0, 0, 0);
      }
      __builtin_amdgcn_s_setprio(0);
    }
  }

  if constexpr (SPLIT == 1) {
    const float inv = 1.0f / lrow;
#pragma unroll
    for (int nb = 0; nb < 8; ++nb) {
      float4 res = {ot[nb][0] * inv, ot[nb][1] * inv, ot[nb][2] * inv,
                    ot[nb][3] * inv};
      *(float4*)(out + (size_t)(q0 + lr) * DK + nb * 16 + lg * 4) = res;
    }
  } else {
    const int row = q0 + lr;
    if (lg == 0) {
      Mpart[(size_t)chunk * M_TOT + row] = mrow;  // log2 units
      Lpart[(size_t)chunk * M_TOT + row] = lrow;
    }
#pragma unroll
    for (int nb = 0; nb < 8; ++nb) {
      ushort4 res;
      res.x = f2bf(ot[nb][0]); res.y = f2bf(ot[nb][1]);
      res.z = f2bf(ot[nb][2]); res.w = f2bf(ot[nb][3]);
      *(ushort4*)(Opart + ((size_t)chunk * M_TOT + row) * DK + nb * 16 +
                  lg * 4) = res;
    }
  }
}

__global__ __launch_bounds__(256) void combine_kernel(
    const unsigned short* __restrict__ Opart, const float* __restrict__ Mpart,
    const float* __restrict__ Lpart, float* __restrict__ out, int split) {
  const int idx = blockIdx.x * 256 + threadIdx.x;  // M_TOT * 32
  const int row = idx >> 5;
  const int cq = (idx & 31) << 2;
  float m = -1e30f;
  for (int s = 0; s < split; ++s) m = fmaxf(m, Mpart[(size_t)s * M_TOT + row]);
  float den = 0.f;
  float4 acc = {0.f, 0.f, 0.f, 0.f};
  for (int s = 0; s < split; ++s) {
    const float w = EXP2(Mpart[(size_t)s * M_TOT + row] - m);  // log2 units
    den += w * Lpart[(size_t)s * M_TOT + row];
    const ushort4 v =
        *(const ushort4*)(Opart + ((size_t)s * M_TOT + row) * DK + cq);
    acc.x += w * bf2f(v.x); acc.y += w * bf2f(v.y);
    acc.z += w * bf2f(v.z); acc.w += w * bf2f(v.w);
  }
  const float inv = 1.0f / den;
  float4 res = {acc.x * inv, acc.y * inv, acc.z * inv, acc.w * inv};
  *(float4*)(out + (size_t)row * DK + cq) = res;
}

extern "C" void kernel_launch(void* const* d_in, const int* in_sizes, int n_in,
                              void* d_out, int out_size, void* d_ws,
                              size_t ws_size, hipStream_t stream) {
  const float* x = (const float*)d_in[0];
  const float* Wq = (const float*)d_in[1];
  const float* bq = (const float*)d_in[2];
  const float* Wk = (const float*)d_in[3];
  const float* bk = (const float*)d_in[4];
  const float* Wv = (const float*)d_in[5];
  const float* bv = (const float*)d_in[6];
  float* out = (float*)d_out;

  unsigned short* Wf = (unsigned short*)d_ws;              // 768 KB
  unsigned short* Qb = Wf + 3 * DK * DIN;                  // 4 MB
  unsigned short* Kb = Qb + (size_t)M_TOT * DK;            // 4 MB
  unsigned short* VT = Kb + (size_t)M_TOT * DK;            // 4 MB
  unsigned short* Opart = VT + (size_t)M_TOT * DK;         // split*4 MB (bf16)
  const size_t base_bytes = 2ull * (3 * DK * DIN + 3ull * M_TOT * DK);
  const size_t per_split = (size_t)M_TOT * DK * 2 + 2ull * M_TOT * 4;

  prep_wt_kernel<<<(3 * DK * DIN) / 256, 256, 0, stream>>>(Wq, Wk, Wv, Wf);
  proj_kernel<<<M_TOT / 64, 512, 0, stream>>>(x, Wf, bq, bk, bv, Qb, Kb, VT);

  int split;
  if (ws_size >= base_bytes + 4 * per_split) split = 4;
  else if (ws_size >= base_bytes + 2 * per_split) split = 2;
  else split = 1;

  float* Mpart = (float*)(Opart + (size_t)split * M_TOT * DK);
  float* Lpart = Mpart + (size_t)split * M_TOT;

  if (split == 4) {
    attn_part_kernel<4><<<128 * 4, 512, 0, stream>>>(Qb, Kb, VT, Opart, Mpart,
                                                     Lpart, out);
    combine_kernel<<<M_TOT * 32 / 256, 256, 0, stream>>>(Opart, Mpart, Lpart,
                                                         out, 4);
  } else if (split == 2) {
    attn_part_kernel<2><<<128 * 2, 512, 0, stream>>>(Qb, Kb, VT, Opart, Mpart,
                                                     Lpart, out);
    combine_kernel<<<M_TOT * 32 / 256, 256, 0, stream>>>(Opart, Mpart, Lpart,
                                                         out, 2);
  } else {
    attn_part_kernel<1><<<128, 512, 0, stream>>>(Qb, Kb, VT, nullptr, nullptr,
                                                 nullptr, out);
  }
}

// Round 23
// 91.884 us; speedup vs baseline: 1.7501x; 1.7501x over previous
//
#include <hip/hip_runtime.h>

#define TB 4
#define TF 4096
#define DIN 1024
#define DK 128
#define M_TOT (TB * TF)  // 16384

typedef __attribute__((ext_vector_type(8))) short sh8;
typedef __attribute__((ext_vector_type(4))) float f32x4;

#if __has_builtin(__builtin_amdgcn_exp2f)
#define EXP2(x) __builtin_amdgcn_exp2f(x)
#else
#define EXP2(x) exp2f(x)
#endif

__device__ __forceinline__ unsigned short f2bf(float f) {
  unsigned int u = __builtin_bit_cast(unsigned int, f);
  u += 0x7FFFu + ((u >> 16) & 1u);
  return (unsigned short)(u >> 16);
}

__device__ __forceinline__ float bf2f(unsigned short u) {
  unsigned int x = ((unsigned int)u) << 16;
  return __builtin_bit_cast(float, x);
}

// Wf in MFMA-fragment order: Wf[((p*8 + t)*32 + ks)*512 + lane*8 + j]
//   = bf16(W_p[k = ks*32 + (lane>>4)*8 + j][col = t*16 + (lane&15)])
__global__ __launch_bounds__(256) void prep_wt_kernel(
    const float* __restrict__ Wq, const float* __restrict__ Wk,
    const float* __restrict__ Wv, unsigned short* __restrict__ Wf) {
  int idx = blockIdx.x * 256 + threadIdx.x;  // [0, 3*8*32*512)
  int j = idx & 7;
  int lane = (idx >> 3) & 63;
  int ks = (idx >> 9) & 31;
  int t = (idx >> 14) & 7;
  int p = idx >> 17;
  int col = t * 16 + (lane & 15);
  int k = ks * 32 + (lane >> 4) * 8 + j;
  const float* W = (p == 0) ? Wq : (p == 1) ? Wk : Wv;
  Wf[idx] = f2bf(W[k * DK + col]);
}

// Fused QKV projection. 512 threads = 8 waves; block = 64 rows of x.
// BK=64, double-buffered x tile, one barrier per tile (R17-proven).
// Wave w owns 16 cols for all 3 projections. Q pre-scaled by
// log2(e)/sqrt(128). V stored transposed.
__global__ __launch_bounds__(512, 2) void proj_kernel(
    const float* __restrict__ x,            // [M_TOT][DIN]
    const unsigned short* __restrict__ Wf,  // fragment-ordered weights
    const float* __restrict__ bq, const float* __restrict__ bk,
    const float* __restrict__ bv,
    unsigned short* __restrict__ Qb,  // [M_TOT][DK] bf16 (pre-scaled)
    unsigned short* __restrict__ Kb,  // [M_TOT][DK] bf16
    unsigned short* __restrict__ VT)  // [TB][DK][TF] bf16
{
  const int tid = threadIdx.x;
  const int wave = tid >> 6;  // 0..7 = col tile
  const int lane = tid & 63;
  const int lr = lane & 15;
  const int lg = lane >> 4;
  const int m0 = blockIdx.x * 64;
  const int col = wave * 16 + lr;

  __shared__ unsigned short Xlds[2][64 * 68];  // [row][k], pad 64->68

  f32x4 acc[3][4];
  const f32x4 z4 = {0.f, 0.f, 0.f, 0.f};
#pragma unroll
  for (int p = 0; p < 3; ++p)
#pragma unroll
    for (int m = 0; m < 4; ++m) acc[p][m] = z4;

  const int xr = tid >> 3;        // 0..63
  const int xk8 = (tid & 7) * 8;  // 0..56
  const float* xrow = x + (size_t)(m0 + xr) * DIN + xk8;

  // prologue: stage tile 0 into buffer 0
  {
    const float4 f0 = *(const float4*)(xrow);
    const float4 f1 = *(const float4*)(xrow + 4);
    union { sh8 v; unsigned short u[8]; } U;
    U.u[0] = f2bf(f0.x); U.u[1] = f2bf(f0.y);
    U.u[2] = f2bf(f0.z); U.u[3] = f2bf(f0.w);
    U.u[4] = f2bf(f1.x); U.u[5] = f2bf(f1.y);
    U.u[6] = f2bf(f1.z); U.u[7] = f2bf(f1.w);
    *(sh8*)&Xlds[0][xr * 68 + xk8] = U.v;
  }
  __syncthreads();

  for (int t = 0; t < DIN / 64; ++t) {
    const int k0 = t * 64;
    const int cur = t & 1;

    // stage tile t+1 into buf^1 (buf^1 free since end of tile t-1)
    if (t + 1 < DIN / 64) {
      const float4 f0 = *(const float4*)(xrow + k0 + 64);
      const float4 f1 = *(const float4*)(xrow + k0 + 68);
      union { sh8 v; unsigned short u[8]; } U;
      U.u[0] = f2bf(f0.x); U.u[1] = f2bf(f0.y);
      U.u[2] = f2bf(f0.z); U.u[3] = f2bf(f0.w);
      U.u[4] = f2bf(f1.x); U.u[5] = f2bf(f1.y);
      U.u[6] = f2bf(f1.z); U.u[7] = f2bf(f1.w);
      *(sh8*)&Xlds[cur ^ 1][xr * 68 + xk8] = U.v;
    }

    sh8 a[4][2];
#pragma unroll
    for (int m = 0; m < 4; ++m)
#pragma unroll
      for (int s = 0; s < 2; ++s)
        a[m][s] =
            *(const sh8*)&Xlds[cur][(m * 16 + lr) * 68 + s * 32 + lg * 8];
#pragma unroll
    for (int p = 0; p < 3; ++p) {
#pragma unroll
      for (int s = 0; s < 2; ++s) {
        sh8 b = *(const sh8*)(Wf +
                              ((size_t)((p * 8 + wave) * 32 + (k0 >> 5) + s)) *
                                  512 +
                              lane * 8);
#pragma unroll
        for (int m = 0; m < 4; ++m)
          acc[p][m] = __builtin_amdgcn_mfma_f32_16x16x32_bf16(a[m][s], b,
                                                              acc[p][m], 0, 0,
                                                              0);
      }
    }
    __syncthreads();  // staging of t+1 visible; reads of cur complete
  }

  // log2(e)/sqrt(128): softmax computed base-2 downstream
  const float scale = 0.12751744f;
  const int b_idx = m0 >> 12;
  const float add_q = bq[col];
  const float add_k = bk[col];
  const float add_v = bv[col];
#pragma unroll
  for (int m = 0; m < 4; ++m) {
    const int rowbase = m0 + m * 16 + lg * 4;
#pragma unroll
    for (int r = 0; r < 4; ++r) {
      Qb[(size_t)(rowbase + r) * DK + col] =
          f2bf((acc[0][m][r] + add_q) * scale);
      Kb[(size_t)(rowbase + r) * DK + col] = f2bf(acc[1][m][r] + add_k);
    }
    const int fbase = (m0 & (TF - 1)) + m * 16 + lg * 4;
    ushort4 pv;
    pv.x = f2bf(acc[2][m][0] + add_v);
    pv.y = f2bf(acc[2][m][1] + add_v);
    pv.z = f2bf(acc[2][m][2] + add_v);
    pv.w = f2bf(acc[2][m][3] + add_v);
    *(ushort4*)(VT + ((size_t)b_idx * DK + col) * TF + fbase) = pv;
  }
}

// Flash attention, split-KV (SPLIT=4, R19/R21-proven best). Single-buffered
// K/V in LDS (both K- and V-from-global measured 2x worse: R22/R4) +
// per-wave P-LDS exchange (4 ds_write_b64 + 2 ds_read_b128 per tile,
// wave-private, lgkmcnt-ordered, no barrier). LDS = 54272 B.
// 8 waves/block, QBLK=16/wave, swapped-operand QK^T, base-2 softmax +
// defer-max + setprio. Partials bf16.
template <int SPLIT>
__global__ __launch_bounds__(512) void attn_part_kernel(
    const unsigned short* __restrict__ Qb, const unsigned short* __restrict__ Kb,
    const unsigned short* __restrict__ VT, unsigned short* __restrict__ Opart,
    float* __restrict__ Mpart, float* __restrict__ Lpart,
    float* __restrict__ out) {
  constexpr int CHUNK = TF / SPLIT;
  const int tid = threadIdx.x;
  const int lane = tid & 63;
  const int lr = lane & 15;
  const int lg = lane >> 4;

  // XCD swizzle: 2 XCDs per batch so K/V (2 MB bf16/batch) stays L2-resident.
  const int bid = blockIdx.x;  // grid = 128*SPLIT
  const int xcd = bid & 7;
  const int batch = xcd >> 1;
  const int idb = ((bid >> 3) << 1) | (xcd & 1);  // 0 .. 32*SPLIT-1
  const int slot = idb / SPLIT;                   // 0..31
  const int chunk = idb % SPLIT;
  const int wave = tid >> 6;  // 0..7
  const int q0 = batch * TF + slot * 128 + wave * 16;
  const int kbase = chunk * CHUNK;

  __shared__ unsigned short Klds[64 * 136];   // 64 kv x 128 d (pad->136)
  __shared__ unsigned short Vlds[128 * 72];   // 128 dv x 64 kv (pad->72)
  __shared__ unsigned short Plds[8][16 * 72]; // per-wave P[q][kv]
  unsigned short* Pw = &Plds[wave][0];

  const unsigned short* Qp = Qb + (size_t)q0 * DK;
  const unsigned short* Kp = Kb + (size_t)batch * TF * DK;
  const unsigned short* Vp = VT + (size_t)batch * DK * TF;

  sh8 aq[4];
#pragma unroll
  for (int dd = 0; dd < 4; ++dd)
    aq[dd] = *(const sh8*)(Qp + lr * DK + dd * 32 + lg * 8);

  const f32x4 z4 = {0.f, 0.f, 0.f, 0.f};
  f32x4 ot[8];  // ot[nb][r] = O^T[d = nb*16 + lg*4 + r][q = lr]
#pragma unroll
  for (int nb = 0; nb < 8; ++nb) ot[nb] = z4;
  float mrow = -1e30f, lrow = 0.f;  // m in log2 units

  for (int kk0 = kbase; kk0 < kbase + CHUNK; kk0 += 64) {
    __syncthreads();
#pragma unroll
    for (int i = 0; i < 2; ++i) {  // stage K tile 64x128 (512 threads)
      int c = tid + i * 512;
      int row = c >> 4, c8 = c & 15;
      *(uint4*)&Klds[row * 136 + c8 * 8] =
          *(const uint4*)(Kp + (size_t)(kk0 + row) * DK + c8 * 8);
    }
#pragma unroll
    for (int i = 0; i < 2; ++i) {  // stage V^T tile 128x64
      int c = tid + i * 512;
      int row = c >> 3, c8 = c & 7;
      *(uint4*)&Vlds[row * 72 + c8 * 8] =
          *(const uint4*)(Vp + (size_t)row * TF + kk0 + c8 * 8);
    }
    __syncthreads();

    // S^T = K Q^T: st[c][r] = S[q=lr][kv = c*16 + lg*4 + r] (log2 units)
    f32x4 st[4];
#pragma unroll
    for (int c = 0; c < 4; ++c) st[c] = z4;
    __builtin_amdgcn_s_setprio(1);
#pragma unroll
    for (int dd = 0; dd < 4; ++dd) {
#pragma unroll
      for (int c = 0; c < 4; ++c) {
        sh8 kb = *(const sh8*)&Klds[(c * 16 + lr) * 136 + dd * 32 + lg * 8];
        st[c] =
            __builtin_amdgcn_mfma_f32_16x16x32_bf16(kb, aq[dd], st[c], 0, 0, 0);
      }
    }
    __builtin_amdgcn_s_setprio(0);

    // online softmax (base-2): lane owns q-row lr; v_max3-friendly tree
    float mx;
    {
      float m0a = fmaxf(fmaxf(st[0][0], st[0][1]), st[0][2]);
      float m0b = fmaxf(fmaxf(st[0][3], st[1][0]), st[1][1]);
      float m0c = fmaxf(fmaxf(st[1][2], st[1][3]), st[2][0]);
      float m0d = fmaxf(fmaxf(st[2][1], st[2][2]), st[2][3]);
      float m0e = fmaxf(fmaxf(st[3][0], st[3][1]), st[3][2]);
      float m1a = fmaxf(fmaxf(m0a, m0b), m0c);
      float m1b = fmaxf(fmaxf(m0d, m0e), st[3][3]);
      mx = fmaxf(m1a, m1b);
    }
    mx = fmaxf(mx, __shfl_xor(mx, 16));
    mx = fmaxf(mx, __shfl_xor(mx, 32));

    // defer-max: skip rescale while tile max stays within THR of running max
    if (!__all(mx - mrow <= 11.5f)) {
      const float mnew = fmaxf(mrow, mx);
      const float al = EXP2(mrow - mnew);
      lrow *= al;
#pragma unroll
      for (int nb = 0; nb < 8; ++nb)
#pragma unroll
        for (int r = 0; r < 4; ++r) ot[nb][r] *= al;
      mrow = mnew;
    }

    // P = exp2(S - m); write P row into wave-private LDS (no barrier needed:
    // same wave writes then reads, lgkmcnt orders it)
    float rs = 0.f;
#pragma unroll
    for (int c = 0; c < 4; ++c) {
      float p0 = EXP2(st[c][0] - mrow);
      float p1 = EXP2(st[c][1] - mrow);
      float p2 = EXP2(st[c][2] - mrow);
      float p3 = EXP2(st[c][3] - mrow);
      rs += p0 + p1 + p2 + p3;
      ushort4 w;
      w.x = f2bf(p0); w.y = f2bf(p1); w.z = f2bf(p2); w.w = f2bf(p3);
      *(ushort4*)&Pw[lr * 72 + c * 16 + lg * 4] = w;
    }
    rs += __shfl_xor(rs, 16);
    rs += __shfl_xor(rs, 32);
    lrow += rs;

    // O^T += V^T P^T; B-fragment pa = P[q=lr][kv=ks*32+lg*8 .. +7] from LDS
#pragma unroll
    for (int ks = 0; ks < 2; ++ks) {
      sh8 pa = *(const sh8*)&Pw[lr * 72 + ks * 32 + lg * 8];
      __builtin_amdgcn_s_setprio(1);
#pragma unroll
      for (int nb = 0; nb < 8; ++nb) {
        sh8 vb = *(const sh8*)&Vlds[(nb * 16 + lr) * 72 + ks * 32 + lg * 8];
        ot[nb] =
            __builtin_amdgcn_mfma_f32_16x16x32_bf16(vb, pa, ot[nb], 0, 0, 0);
      }
      __builtin_amdgcn_s_setprio(0);
    }
  }

  if constexpr (SPLIT == 1) {
    const float inv = 1.0f / lrow;
#pragma unroll
    for (int nb = 0; nb < 8; ++nb) {
      float4 res = {ot[nb][0] * inv, ot[nb][1] * inv, ot[nb][2] * inv,
                    ot[nb][3] * inv};
      *(float4*)(out + (size_t)(q0 + lr) * DK + nb * 16 + lg * 4) = res;
    }
  } else {
    const int row = q0 + lr;
    if (lg == 0) {
      Mpart[(size_t)chunk * M_TOT + row] = mrow;  // log2 units
      Lpart[(size_t)chunk * M_TOT + row] = lrow;
    }
#pragma unroll
    for (int nb = 0; nb < 8; ++nb) {
      ushort4 res;
      res.x = f2bf(ot[nb][0]); res.y = f2bf(ot[nb][1]);
      res.z = f2bf(ot[nb][2]); res.w = f2bf(ot[nb][3]);
      *(ushort4*)(Opart + ((size_t)chunk * M_TOT + row) * DK + nb * 16 +
                  lg * 4) = res;
    }
  }
}

__global__ __launch_bounds__(256) void combine_kernel(
    const unsigned short* __restrict__ Opart, const float* __restrict__ Mpart,
    const float* __restrict__ Lpart, float* __restrict__ out, int split) {
  const int idx = blockIdx.x * 256 + threadIdx.x;  // M_TOT * 32
  const int row = idx >> 5;
  const int cq = (idx & 31) << 2;
  float m = -1e30f;
  for (int s = 0; s < split; ++s) m = fmaxf(m, Mpart[(size_t)s * M_TOT + row]);
  float den = 0.f;
  float4 acc = {0.f, 0.f, 0.f, 0.f};
  for (int s = 0; s < split; ++s) {
    const float w = EXP2(Mpart[(size_t)s * M_TOT + row] - m);  // log2 units
    den += w * Lpart[(size_t)s * M_TOT + row];
    const ushort4 v =
        *(const ushort4*)(Opart + ((size_t)s * M_TOT + row) * DK + cq);
    acc.x += w * bf2f(v.x); acc.y += w * bf2f(v.y);
    acc.z += w * bf2f(v.z); acc.w += w * bf2f(v.w);
  }
  const float inv = 1.0f / den;
  float4 res = {acc.x * inv, acc.y * inv, acc.z * inv, acc.w * inv};
  *(float4*)(out + (size_t)row * DK + cq) = res;
}

extern "C" void kernel_launch(void* const* d_in, const int* in_sizes, int n_in,
                              void* d_out, int out_size, void* d_ws,
                              size_t ws_size, hipStream_t stream) {
  const float* x = (const float*)d_in[0];
  const float* Wq = (const float*)d_in[1];
  const float* bq = (const float*)d_in[2];
  const float* Wk = (const float*)d_in[3];
  const float* bk = (const float*)d_in[4];
  const float* Wv = (const float*)d_in[5];
  const float* bv = (const float*)d_in[6];
  float* out = (float*)d_out;

  unsigned short* Wf = (unsigned short*)d_ws;              // 768 KB
  unsigned short* Qb = Wf + 3 * DK * DIN;                  // 4 MB
  unsigned short* Kb = Qb + (size_t)M_TOT * DK;            // 4 MB
  unsigned short* VT = Kb + (size_t)M_TOT * DK;            // 4 MB
  unsigned short* Opart = VT + (size_t)M_TOT * DK;         // split*4 MB (bf16)
  const size_t base_bytes = 2ull * (3 * DK * DIN + 3ull * M_TOT * DK);
  const size_t per_split = (size_t)M_TOT * DK * 2 + 2ull * M_TOT * 4;

  prep_wt_kernel<<<(3 * DK * DIN) / 256, 256, 0, stream>>>(Wq, Wk, Wv, Wf);
  proj_kernel<<<M_TOT / 64, 512, 0, stream>>>(x, Wf, bq, bk, bv, Qb, Kb, VT);

  int split;
  if (ws_size >= base_bytes + 4 * per_split) split = 4;
  else if (ws_size >= base_bytes + 2 * per_split) split = 2;
  else split = 1;

  float* Mpart = (float*)(Opart + (size_t)split * M_TOT * DK);
  float* Lpart = Mpart + (size_t)split * M_TOT;

  if (split == 4) {
    attn_part_kernel<4><<<128 * 4, 512, 0, stream>>>(Qb, Kb, VT, Opart, Mpart,
                                                     Lpart, out);
    combine_kernel<<<M_TOT * 32 / 256, 256, 0, stream>>>(Opart, Mpart, Lpart,
                                                         out, 4);
  } else if (split == 2) {
    attn_part_kernel<2><<<128 * 2, 512, 0, stream>>>(Qb, Kb, VT, Opart, Mpart,
                                                     Lpart, out);
    combine_kernel<<<M_TOT * 32 / 256, 256, 0, stream>>>(Opart, Mpart, Lpart,
                                                         out, 2);
  } else {
    attn_part_kernel<1><<<128, 512, 0, stream>>>(Qb, Kb, VT, nullptr, nullptr,
                                                 nullptr, out);
  }
}

// Round 24
// 89.910 us; speedup vs baseline: 1.7885x; 1.0220x over previous
//
#include <hip/hip_runtime.h>

#define TB 4
#define TF 4096
#define DIN 1024
#define DK 128
#define M_TOT (TB * TF)  // 16384

typedef __attribute__((ext_vector_type(8))) short sh8;
typedef __attribute__((ext_vector_type(4))) float f32x4;

#if __has_builtin(__builtin_amdgcn_exp2f)
#define EXP2(x) __builtin_amdgcn_exp2f(x)
#else
#define EXP2(x) exp2f(x)
#endif

__device__ __forceinline__ unsigned short f2bf(float f) {
  unsigned int u = __builtin_bit_cast(unsigned int, f);
  u += 0x7FFFu + ((u >> 16) & 1u);
  return (unsigned short)(u >> 16);
}

__device__ __forceinline__ float bf2f(unsigned short u) {
  unsigned int x = ((unsigned int)u) << 16;
  return __builtin_bit_cast(float, x);
}

// Wf in MFMA-fragment order: Wf[((p*8 + t)*32 + ks)*512 + lane*8 + j]
//   = bf16(W_p[k = ks*32 + (lane>>4)*8 + j][col = t*16 + (lane&15)])
__global__ __launch_bounds__(256) void prep_wt_kernel(
    const float* __restrict__ Wq, const float* __restrict__ Wk,
    const float* __restrict__ Wv, unsigned short* __restrict__ Wf) {
  int idx = blockIdx.x * 256 + threadIdx.x;  // [0, 3*8*32*512)
  int j = idx & 7;
  int lane = (idx >> 3) & 63;
  int ks = (idx >> 9) & 31;
  int t = (idx >> 14) & 7;
  int p = idx >> 17;
  int col = t * 16 + (lane & 15);
  int k = ks * 32 + (lane >> 4) * 8 + j;
  const float* W = (p == 0) ? Wq : (p == 1) ? Wk : Wv;
  Wf[idx] = f2bf(W[k * DK + col]);
}

// Fused QKV projection. 512 threads = 8 waves; block = 64 rows of x.
// BK=64, double-buffered x tile, one barrier per tile (R17-proven).
// Wave w owns 16 cols for all 3 projections. Q pre-scaled by
// log2(e)/sqrt(128). V stored transposed.
__global__ __launch_bounds__(512, 2) void proj_kernel(
    const float* __restrict__ x,            // [M_TOT][DIN]
    const unsigned short* __restrict__ Wf,  // fragment-ordered weights
    const float* __restrict__ bq, const float* __restrict__ bk,
    const float* __restrict__ bv,
    unsigned short* __restrict__ Qb,  // [M_TOT][DK] bf16 (pre-scaled)
    unsigned short* __restrict__ Kb,  // [M_TOT][DK] bf16
    unsigned short* __restrict__ VT)  // [TB][DK][TF] bf16
{
  const int tid = threadIdx.x;
  const int wave = tid >> 6;  // 0..7 = col tile
  const int lane = tid & 63;
  const int lr = lane & 15;
  const int lg = lane >> 4;
  const int m0 = blockIdx.x * 64;
  const int col = wave * 16 + lr;

  __shared__ unsigned short Xlds[2][64 * 68];  // [row][k], pad 64->68

  f32x4 acc[3][4];
  const f32x4 z4 = {0.f, 0.f, 0.f, 0.f};
#pragma unroll
  for (int p = 0; p < 3; ++p)
#pragma unroll
    for (int m = 0; m < 4; ++m) acc[p][m] = z4;

  const int xr = tid >> 3;        // 0..63
  const int xk8 = (tid & 7) * 8;  // 0..56
  const float* xrow = x + (size_t)(m0 + xr) * DIN + xk8;

  // prologue: stage tile 0 into buffer 0
  {
    const float4 f0 = *(const float4*)(xrow);
    const float4 f1 = *(const float4*)(xrow + 4);
    union { sh8 v; unsigned short u[8]; } U;
    U.u[0] = f2bf(f0.x); U.u[1] = f2bf(f0.y);
    U.u[2] = f2bf(f0.z); U.u[3] = f2bf(f0.w);
    U.u[4] = f2bf(f1.x); U.u[5] = f2bf(f1.y);
    U.u[6] = f2bf(f1.z); U.u[7] = f2bf(f1.w);
    *(sh8*)&Xlds[0][xr * 68 + xk8] = U.v;
  }
  __syncthreads();

  for (int t = 0; t < DIN / 64; ++t) {
    const int k0 = t * 64;
    const int cur = t & 1;

    // stage tile t+1 into buf^1 (buf^1 free since end of tile t-1)
    if (t + 1 < DIN / 64) {
      const float4 f0 = *(const float4*)(xrow + k0 + 64);
      const float4 f1 = *(const float4*)(xrow + k0 + 68);
      union { sh8 v; unsigned short u[8]; } U;
      U.u[0] = f2bf(f0.x); U.u[1] = f2bf(f0.y);
      U.u[2] = f2bf(f0.z); U.u[3] = f2bf(f0.w);
      U.u[4] = f2bf(f1.x); U.u[5] = f2bf(f1.y);
      U.u[6] = f2bf(f1.z); U.u[7] = f2bf(f1.w);
      *(sh8*)&Xlds[cur ^ 1][xr * 68 + xk8] = U.v;
    }

    sh8 a[4][2];
#pragma unroll
    for (int m = 0; m < 4; ++m)
#pragma unroll
      for (int s = 0; s < 2; ++s)
        a[m][s] =
            *(const sh8*)&Xlds[cur][(m * 16 + lr) * 68 + s * 32 + lg * 8];
#pragma unroll
    for (int p = 0; p < 3; ++p) {
#pragma unroll
      for (int s = 0; s < 2; ++s) {
        sh8 b = *(const sh8*)(Wf +
                              ((size_t)((p * 8 + wave) * 32 + (k0 >> 5) + s)) *
                                  512 +
                              lane * 8);
#pragma unroll
        for (int m = 0; m < 4; ++m)
          acc[p][m] = __builtin_amdgcn_mfma_f32_16x16x32_bf16(a[m][s], b,
                                                              acc[p][m], 0, 0,
                                                              0);
      }
    }
    __syncthreads();  // staging of t+1 visible; reads of cur complete
  }

  // log2(e)/sqrt(128): softmax computed base-2 downstream
  const float scale = 0.12751744f;
  const int b_idx = m0 >> 12;
  const float add_q = bq[col];
  const float add_k = bk[col];
  const float add_v = bv[col];
#pragma unroll
  for (int m = 0; m < 4; ++m) {
    const int rowbase = m0 + m * 16 + lg * 4;
#pragma unroll
    for (int r = 0; r < 4; ++r) {
      Qb[(size_t)(rowbase + r) * DK + col] =
          f2bf((acc[0][m][r] + add_q) * scale);
      Kb[(size_t)(rowbase + r) * DK + col] = f2bf(acc[1][m][r] + add_k);
    }
    const int fbase = (m0 & (TF - 1)) + m * 16 + lg * 4;
    ushort4 pv;
    pv.x = f2bf(acc[2][m][0] + add_v);
    pv.y = f2bf(acc[2][m][1] + add_v);
    pv.z = f2bf(acc[2][m][2] + add_v);
    pv.w = f2bf(acc[2][m][3] + add_v);
    *(ushort4*)(VT + ((size_t)b_idx * DK + col) * TF + fbase) = pv;
  }
}

// Flash attention, split-KV (SPLIT=4). Single-buffered K/V in LDS + per-wave
// P-LDS exchange (R21-proven). NEW: zero cross-lane ops in the common path —
// per-lane partial row-sum (lpart, reduced once at the end) and the row-max
// shfl reduce runs only inside the (rare) rescale branch; the defer check
// __all(mx16 - mrow <= THR) on the UNREDUCED per-lane max is equivalent.
// LDS = 54272 B. 8 waves/block, QBLK=16/wave, swapped-operand QK^T,
// base-2 softmax + defer-max + setprio. Partials bf16.
template <int SPLIT>
__global__ __launch_bounds__(512) void attn_part_kernel(
    const unsigned short* __restrict__ Qb, const unsigned short* __restrict__ Kb,
    const unsigned short* __restrict__ VT, unsigned short* __restrict__ Opart,
    float* __restrict__ Mpart, float* __restrict__ Lpart,
    float* __restrict__ out) {
  constexpr int CHUNK = TF / SPLIT;
  const int tid = threadIdx.x;
  const int lane = tid & 63;
  const int lr = lane & 15;
  const int lg = lane >> 4;

  // XCD swizzle: 2 XCDs per batch so K/V (2 MB bf16/batch) stays L2-resident.
  const int bid = blockIdx.x;  // grid = 128*SPLIT
  const int xcd = bid & 7;
  const int batch = xcd >> 1;
  const int idb = ((bid >> 3) << 1) | (xcd & 1);  // 0 .. 32*SPLIT-1
  const int slot = idb / SPLIT;                   // 0..31
  const int chunk = idb % SPLIT;
  const int wave = tid >> 6;  // 0..7
  const int q0 = batch * TF + slot * 128 + wave * 16;
  const int kbase = chunk * CHUNK;

  __shared__ unsigned short Klds[64 * 136];   // 64 kv x 128 d (pad->136)
  __shared__ unsigned short Vlds[128 * 72];   // 128 dv x 64 kv (pad->72)
  __shared__ unsigned short Plds[8][16 * 72]; // per-wave P[q][kv]
  unsigned short* Pw = &Plds[wave][0];

  const unsigned short* Qp = Qb + (size_t)q0 * DK;
  const unsigned short* Kp = Kb + (size_t)batch * TF * DK;
  const unsigned short* Vp = VT + (size_t)batch * DK * TF;

  sh8 aq[4];
#pragma unroll
  for (int dd = 0; dd < 4; ++dd)
    aq[dd] = *(const sh8*)(Qp + lr * DK + dd * 32 + lg * 8);

  const f32x4 z4 = {0.f, 0.f, 0.f, 0.f};
  f32x4 ot[8];  // ot[nb][r] = O^T[d = nb*16 + lg*4 + r][q = lr]
#pragma unroll
  for (int nb = 0; nb < 8; ++nb) ot[nb] = z4;
  float mrow = -1e30f;   // running max, log2 units (lane-uniform per row)
  float lpart = 0.f;     // per-lane partial row sum (reduced at the end)

  for (int kk0 = kbase; kk0 < kbase + CHUNK; kk0 += 64) {
    __syncthreads();
#pragma unroll
    for (int i = 0; i < 2; ++i) {  // stage K tile 64x128 (512 threads)
      int c = tid + i * 512;
      int row = c >> 4, c8 = c & 15;
      *(uint4*)&Klds[row * 136 + c8 * 8] =
          *(const uint4*)(Kp + (size_t)(kk0 + row) * DK + c8 * 8);
    }
#pragma unroll
    for (int i = 0; i < 2; ++i) {  // stage V^T tile 128x64
      int c = tid + i * 512;
      int row = c >> 3, c8 = c & 7;
      *(uint4*)&Vlds[row * 72 + c8 * 8] =
          *(const uint4*)(Vp + (size_t)row * TF + kk0 + c8 * 8);
    }
    __syncthreads();

    // S^T = K Q^T: st[c][r] = S[q=lr][kv = c*16 + lg*4 + r] (log2 units)
    f32x4 st[4];
#pragma unroll
    for (int c = 0; c < 4; ++c) st[c] = z4;
    __builtin_amdgcn_s_setprio(1);
#pragma unroll
    for (int dd = 0; dd < 4; ++dd) {
#pragma unroll
      for (int c = 0; c < 4; ++c) {
        sh8 kb = *(const sh8*)&Klds[(c * 16 + lr) * 136 + dd * 32 + lg * 8];
        st[c] =
            __builtin_amdgcn_mfma_f32_16x16x32_bf16(kb, aq[dd], st[c], 0, 0, 0);
      }
    }
    __builtin_amdgcn_s_setprio(0);

    // per-lane max of this lane's 16 values (v_max3-friendly tree);
    // NO cross-lane reduce in the common path
    float mx16;
    {
      float m0a = fmaxf(fmaxf(st[0][0], st[0][1]), st[0][2]);
      float m0b = fmaxf(fmaxf(st[0][3], st[1][0]), st[1][1]);
      float m0c = fmaxf(fmaxf(st[1][2], st[1][3]), st[2][0]);
      float m0d = fmaxf(fmaxf(st[2][1], st[2][2]), st[2][3]);
      float m0e = fmaxf(fmaxf(st[3][0], st[3][1]), st[3][2]);
      float m1a = fmaxf(fmaxf(m0a, m0b), m0c);
      float m1b = fmaxf(fmaxf(m0d, m0e), st[3][3]);
      mx16 = fmaxf(m1a, m1b);
    }

    // defer-max: __all over unreduced per-lane max == check on row max.
    // Reduce + rescale only when some row actually grew past THR.
    if (!__all(mx16 - mrow <= 11.5f)) {
      float mxr = fmaxf(mx16, __shfl_xor(mx16, 16));
      mxr = fmaxf(mxr, __shfl_xor(mxr, 32));
      const float mnew = fmaxf(mrow, mxr);
      const float al = EXP2(mrow - mnew);
      lpart *= al;
#pragma unroll
      for (int nb = 0; nb < 8; ++nb)
#pragma unroll
        for (int r = 0; r < 4; ++r) ot[nb][r] *= al;
      mrow = mnew;
    }

    // P = exp2(S - m); accumulate per-lane partial sum; write P row into
    // wave-private LDS (no barrier: same wave writes then reads)
#pragma unroll
    for (int c = 0; c < 4; ++c) {
      float p0 = EXP2(st[c][0] - mrow);
      float p1 = EXP2(st[c][1] - mrow);
      float p2 = EXP2(st[c][2] - mrow);
      float p3 = EXP2(st[c][3] - mrow);
      lpart += p0 + p1 + p2 + p3;
      ushort4 w;
      w.x = f2bf(p0); w.y = f2bf(p1); w.z = f2bf(p2); w.w = f2bf(p3);
      *(ushort4*)&Pw[lr * 72 + c * 16 + lg * 4] = w;
    }

    // O^T += V^T P^T; B-fragment pa = P[q=lr][kv=ks*32+lg*8 .. +7] from LDS
#pragma unroll
    for (int ks = 0; ks < 2; ++ks) {
      sh8 pa = *(const sh8*)&Pw[lr * 72 + ks * 32 + lg * 8];
      __builtin_amdgcn_s_setprio(1);
#pragma unroll
      for (int nb = 0; nb < 8; ++nb) {
        sh8 vb = *(const sh8*)&Vlds[(nb * 16 + lr) * 72 + ks * 32 + lg * 8];
        ot[nb] =
            __builtin_amdgcn_mfma_f32_16x16x32_bf16(vb, pa, ot[nb], 0, 0, 0);
      }
      __builtin_amdgcn_s_setprio(0);
    }
  }

  // epilogue: reduce the per-lane partial row sums once
  float lrow = lpart + __shfl_xor(lpart, 16);
  lrow += __shfl_xor(lrow, 32);

  if constexpr (SPLIT == 1) {
    const float inv = 1.0f / lrow;
#pragma unroll
    for (int nb = 0; nb < 8; ++nb) {
      float4 res = {ot[nb][0] * inv, ot[nb][1] * inv, ot[nb][2] * inv,
                    ot[nb][3] * inv};
      *(float4*)(out + (size_t)(q0 + lr) * DK + nb * 16 + lg * 4) = res;
    }
  } else {
    const int row = q0 + lr;
    if (lg == 0) {
      Mpart[(size_t)chunk * M_TOT + row] = mrow;  // log2 units
      Lpart[(size_t)chunk * M_TOT + row] = lrow;
    }
#pragma unroll
    for (int nb = 0; nb < 8; ++nb) {
      ushort4 res;
      res.x = f2bf(ot[nb][0]); res.y = f2bf(ot[nb][1]);
      res.z = f2bf(ot[nb][2]); res.w = f2bf(ot[nb][3]);
      *(ushort4*)(Opart + ((size_t)chunk * M_TOT + row) * DK + nb * 16 +
                  lg * 4) = res;
    }
  }
}

__global__ __launch_bounds__(256) void combine_kernel(
    const unsigned short* __restrict__ Opart, const float* __restrict__ Mpart,
    const float* __restrict__ Lpart, float* __restrict__ out, int split) {
  const int idx = blockIdx.x * 256 + threadIdx.x;  // M_TOT * 32
  const int row = idx >> 5;
  const int cq = (idx & 31) << 2;
  float m = -1e30f;
  for (int s = 0; s < split; ++s) m = fmaxf(m, Mpart[(size_t)s * M_TOT + row]);
  float den = 0.f;
  float4 acc = {0.f, 0.f, 0.f, 0.f};
  for (int s = 0; s < split; ++s) {
    const float w = EXP2(Mpart[(size_t)s * M_TOT + row] - m);  // log2 units
    den += w * Lpart[(size_t)s * M_TOT + row];
    const ushort4 v =
        *(const ushort4*)(Opart + ((size_t)s * M_TOT + row) * DK + cq);
    acc.x += w * bf2f(v.x); acc.y += w * bf2f(v.y);
    acc.z += w * bf2f(v.z); acc.w += w * bf2f(v.w);
  }
  const float inv = 1.0f / den;
  float4 res = {acc.x * inv, acc.y * inv, acc.z * inv, acc.w * inv};
  *(float4*)(out + (size_t)row * DK + cq) = res;
}

extern "C" void kernel_launch(void* const* d_in, const int* in_sizes, int n_in,
                              void* d_out, int out_size, void* d_ws,
                              size_t ws_size, hipStream_t stream) {
  const float* x = (const float*)d_in[0];
  const float* Wq = (const float*)d_in[1];
  const float* bq = (const float*)d_in[2];
  const float* Wk = (const float*)d_in[3];
  const float* bk = (const float*)d_in[4];
  const float* Wv = (const float*)d_in[5];
  const float* bv = (const float*)d_in[6];
  float* out = (float*)d_out;

  unsigned short* Wf = (unsigned short*)d_ws;              // 768 KB
  unsigned short* Qb = Wf + 3 * DK * DIN;                  // 4 MB
  unsigned short* Kb = Qb + (size_t)M_TOT * DK;            // 4 MB
  unsigned short* VT = Kb + (size_t)M_TOT * DK;            // 4 MB
  unsigned short* Opart = VT + (size_t)M_TOT * DK;         // split*4 MB (bf16)
  const size_t base_bytes = 2ull * (3 * DK * DIN + 3ull * M_TOT * DK);
  const size_t per_split = (size_t)M_TOT * DK * 2 + 2ull * M_TOT * 4;

  prep_wt_kernel<<<(3 * DK * DIN) / 256, 256, 0, stream>>>(Wq, Wk, Wv, Wf);
  proj_kernel<<<M_TOT / 64, 512, 0, stream>>>(x, Wf, bq, bk, bv, Qb, Kb, VT);

  int split;
  if (ws_size >= base_bytes + 4 * per_split) split = 4;
  else if (ws_size >= base_bytes + 2 * per_split) split = 2;
  else split = 1;

  float* Mpart = (float*)(Opart + (size_t)split * M_TOT * DK);
  float* Lpart = Mpart + (size_t)split * M_TOT;

  if (split == 4) {
    attn_part_kernel<4><<<128 * 4, 512, 0, stream>>>(Qb, Kb, VT, Opart, Mpart,
                                                     Lpart, out);
    combine_kernel<<<M_TOT * 32 / 256, 256, 0, stream>>>(Opart, Mpart, Lpart,
                                                         out, 4);
  } else if (split == 2) {
    attn_part_kernel<2><<<128 * 2, 512, 0, stream>>>(Qb, Kb, VT, Opart, Mpart,
                                                     Lpart, out);
    combine_kernel<<<M_TOT * 32 / 256, 256, 0, stream>>>(Opart, Mpart, Lpart,
                                                         out, 2);
  } else {
    attn_part_kernel<1><<<128, 512, 0, stream>>>(Qb, Kb, VT, nullptr, nullptr,
                                                 nullptr, out);
  }
}